// Round 4
// baseline (335.130 us; speedup 1.0000x reference)
//
#include <hip/hip_runtime.h>
#include <math.h>

// LiquidEchoHead, two barrier-free streaming kernels.
//
// A: one 64-lane wave per row computes alpha[row] (interference reduction).
//    No __syncthreads; wave-level __shfl_xor butterfly only.
// B: block-per-row elementwise evolve; nontemporal output stores keep
//    x/mem resident in L2/L3.
// Identity: cos(a)cos(b)-sin(a)sin(b)=cos(a+b); cos(a)sin(b)+sin(a)cos(b)=sin(a+b)
// -> evolve needs one sincos on the summed angle.

#define PHI_F 1.61803398874989f

typedef float vfloat4 __attribute__((ext_vector_type(4)));

__global__ __launch_bounds__(256) void alpha_kernel(
    const float* __restrict__ x_real, const float* __restrict__ x_imag,
    const float* __restrict__ w_query, const float* __restrict__ b_query,
    float* __restrict__ alpha_out, float inv_scale, int d4)
{
    const int wave = threadIdx.x >> 6;
    const int lane = threadIdx.x & 63;
    const int row  = (blockIdx.x << 2) + wave;
    const size_t base4 = (size_t)row * d4;

    const float4* xr4 = (const float4*)x_real + base4;
    const float4* xi4 = (const float4*)x_imag + base4;
    const float4* wq4 = (const float4*)w_query;
    const float4* bq4 = (const float4*)b_query;

    float accR = 0.f, accI = 0.f;
    #pragma unroll 4
    for (int c = lane; c < d4; c += 64) {
        float4 xr = xr4[c];
        float4 xi = xi4[c];
        float4 wq = wq4[c];
        float4 bq = bq4[c];
        #pragma unroll
        for (int j = 0; j < 4; ++j) {
            float xrv = (&xr.x)[j];
            float xiv = (&xi.x)[j];
            float wl  = 1.f + fabsf((&wq.x)[j]);
            float theta = xrv * __builtin_amdgcn_rcpf(wl) + (&bq.x)[j];
            float sv, cv;
            __sincosf(theta, &sv, &cv);
            accR = fmaf(cv, xrv, fmaf(sv, xiv, accR));
            accI = fmaf(cv, xiv, fmaf(-sv, xrv, accI));
        }
    }

    #pragma unroll
    for (int off = 32; off; off >>= 1) {
        accR += __shfl_xor(accR, off);
        accI += __shfl_xor(accI, off);
    }

    if (lane == 0) {
        float interf = sqrtf(fmaf(accR, accR, accI * accI));
        float z   = fmaf(interf, inv_scale, -2.0f);
        float sig = 1.f / (1.f + __expf(-z));
        alpha_out[row] = __expf(-(1.f - sig));   // exp(-k*(1-sig)), k=1
    }
}

__global__ __launch_bounds__(256) void evolve_kernel(
    const float* __restrict__ x_real, const float* __restrict__ x_imag,
    const float* __restrict__ t_arr,
    const float* __restrict__ w_osc, const float* __restrict__ b_osc,
    const float* __restrict__ mem_r, const float* __restrict__ mem_i,
    const float* __restrict__ alpha_in,
    float* __restrict__ out_r, float* __restrict__ out_i, int d4)
{
    const int row = blockIdx.x;
    const size_t base4 = (size_t)row * d4;

    const float alpha = alpha_in[row];
    const float beta  = 1.f - alpha;
    const float tphi2 = 2.0f * PHI_F * t_arr[row];

    const float4* xr4 = (const float4*)x_real + base4;
    const float4* xi4 = (const float4*)x_imag + base4;
    const float4* mr4 = (const float4*)mem_r + base4;
    const float4* mi4 = (const float4*)mem_i + base4;
    const float4* wo4 = (const float4*)w_osc;
    const float4* bo4 = (const float4*)b_osc;
    vfloat4* or4 = (vfloat4*)out_r + base4;
    vfloat4* oi4 = (vfloat4*)out_i + base4;

    #pragma unroll 2
    for (int c = (int)threadIdx.x; c < d4; c += 256) {
        float4 xr = xr4[c];
        float4 xi = xi4[c];
        float4 mr = mr4[c];
        float4 mi = mi4[c];
        float4 wo = wo4[c];
        float4 bo = bo4[c];
        vfloat4 oR, oI;
        #pragma unroll
        for (int j = 0; j < 4; ++j) {
            float br = fmaf(alpha, (&xr.x)[j], beta * (&mr.x)[j]);
            float bi = fmaf(alpha, (&xi.x)[j], beta * (&mi.x)[j]);
            float wl = 1.f + fabsf((&wo.x)[j]);
            float ang = fmaf(br + bi, __builtin_amdgcn_rcpf(wl),
                             fmaf(2.f, (&bo.x)[j], tphi2));
            float sv, cv;
            __sincosf(ang, &sv, &cv);
            oR[j] = cv;   // evolved_real = cos(th_r + th_i)
            oI[j] = sv;   // evolved_imag = sin(th_r + th_i)
        }
        __builtin_nontemporal_store(oR, &or4[c]);
        __builtin_nontemporal_store(oI, &oi4[c]);
    }
}

extern "C" void kernel_launch(void* const* d_in, const int* in_sizes, int n_in,
                              void* d_out, int out_size, void* d_ws, size_t ws_size,
                              hipStream_t stream) {
    const float* x_real   = (const float*)d_in[0];
    const float* x_imag   = (const float*)d_in[1];
    const float* t_arr    = (const float*)d_in[2];
    const float* w_query  = (const float*)d_in[3];
    const float* b_query  = (const float*)d_in[4];
    const float* w_osc    = (const float*)d_in[5];
    const float* b_osc    = (const float*)d_in[6];
    const float* mem_r    = (const float*)d_in[7];
    const float* mem_i    = (const float*)d_in[8];

    const int B = in_sizes[2];   // t is [B]
    const int D = in_sizes[3];   // w_query is [D]
    const int d4 = D >> 2;

    float* out_r = (float*)d_out;
    float* out_i = out_r + (size_t)B * D;
    float* alpha_buf = (float*)d_ws;   // B floats of scratch

    const float inv_scale = 1.0f / sqrtf((float)D);

    alpha_kernel<<<B / 4, 256, 0, stream>>>(
        x_real, x_imag, w_query, b_query, alpha_buf, inv_scale, d4);

    evolve_kernel<<<B, 256, 0, stream>>>(
        x_real, x_imag, t_arr, w_osc, b_osc, mem_r, mem_i,
        alpha_buf, out_r, out_i, d4);
}